// Round 1
// baseline (223.356 us; speedup 1.0000x reference)
//
#include <hip/hip_runtime.h>

typedef _Float16 f16;
typedef __attribute__((ext_vector_type(8))) _Float16 f16x8;
typedef __attribute__((ext_vector_type(4))) float f32x4;

#define SEQ   4096
#define NH    16
#define HD    80
#define HIDN  1280
#define DP    96      // padded head dim (3 x K=32 MFMA steps)
#define KROWS 104     // K-tile LDS row stride (208B = 13 chunks -> 2-way bank alias)
#define VROWS 56      // V-tile LDS row stride (112B = 7 chunks  -> 2-way)
#define PROWS 56      // P-buffer row stride

__device__ __forceinline__ void gload16(const void* g, void* l) {
  __builtin_amdgcn_global_load_lds(
      (const __attribute__((address_space(1))) unsigned int*)g,
      (__attribute__((address_space(3))) unsigned int*)l, 16, 0, 0);
}

// ---------------- f32 -> f16 convert (n % 8 == 0) ----------------
__global__ __launch_bounds__(256) void cvt_kernel(const float* __restrict__ s,
                                                  f16* __restrict__ d, int n) {
  int base = (blockIdx.x * 256 + threadIdx.x) * 8;
  if (base >= n) return;
  f32x4 v0 = *(const f32x4*)(s + base);
  f32x4 v1 = *(const f32x4*)(s + base + 4);
  f16x8 o;
#pragma unroll
  for (int j = 0; j < 4; j++) { o[j] = (f16)v0[j]; o[4 + j] = (f16)v1[j]; }
  *(f16x8*)(d + base) = o;
}

// ---------------- GEMM: C[M][N] = A[M][K] * B[N][K]^T + bias ----------------
// 128x128 tile, BK=32, 4 waves (2x2 of 64x64), global_load_lds staging (m97 structure).
template<int OUT_F32>
__global__ __launch_bounds__(256) void gemm_bt(const f16* __restrict__ A,
                                               const f16* __restrict__ B,
                                               const float* __restrict__ bias,
                                               void* __restrict__ C,
                                               int M, int N, int K) {
  __shared__ __align__(16) f16 As[128 * 32];
  __shared__ __align__(16) f16 Bs[128 * 32];
  const int tid = threadIdx.x;
  const int w = tid >> 6, l = tid & 63;
  const int m0 = blockIdx.y * 128, n0 = blockIdx.x * 128;
  const int wm = (w >> 1) * 64, wn = (w & 1) * 64;

  // staging: 512 16B-chunks per matrix; chunk c -> row=c>>2, 8-elem group g=c&3
  const int c0 = w * 64 + l;
  const int c1 = (4 + w) * 64 + l;
  const size_t a0 = (size_t)(m0 + (c0 >> 2)) * K + (c0 & 3) * 8;
  const size_t a1 = (size_t)(m0 + (c1 >> 2)) * K + (c1 & 3) * 8;
  const size_t b0 = (size_t)(n0 + (c0 >> 2)) * K + (c0 & 3) * 8;
  const size_t b1 = (size_t)(n0 + (c1 >> 2)) * K + (c1 & 3) * 8;

  f32x4 acc[4][4] = {};
  const int fr = l & 15, fg = (l >> 4) * 8;

  for (int k0 = 0; k0 < K; k0 += 32) {
    if (k0) __syncthreads();
    gload16(A + a0 + k0, As + w * 512);        // LDS dest: wave-uniform base + lane*16
    gload16(A + a1 + k0, As + (4 + w) * 512);
    gload16(B + b0 + k0, Bs + w * 512);
    gload16(B + b1 + k0, Bs + (4 + w) * 512);
    __syncthreads();
    f16x8 af[4], bf[4];
#pragma unroll
    for (int i = 0; i < 4; i++)
      af[i] = *(const f16x8*)(As + (wm + i * 16 + fr) * 32 + fg);
#pragma unroll
    for (int j = 0; j < 4; j++)
      bf[j] = *(const f16x8*)(Bs + (wn + j * 16 + fr) * 32 + fg);
#pragma unroll
    for (int i = 0; i < 4; i++)
#pragma unroll
      for (int j = 0; j < 4; j++)
        acc[i][j] = __builtin_amdgcn_mfma_f32_16x16x32_f16(af[i], bf[j], acc[i][j], 0, 0, 0);
  }

  // C/D layout: col = lane&15, row = (lane>>4)*4 + reg   [m89 verified]
  const int q4 = (l >> 4) * 4;
#pragma unroll
  for (int i = 0; i < 4; i++) {
    const int row = m0 + wm + i * 16 + q4;
#pragma unroll
    for (int j = 0; j < 4; j++) {
      const int col = n0 + wn + j * 16 + fr;
      const float bv = bias[col];
#pragma unroll
      for (int q = 0; q < 4; q++) {
        float v = acc[i][j][q] + bv;
        if (OUT_F32) ((float*)C)[(size_t)(row + q) * N + col] = v;
        else         ((f16*)C)[(size_t)(row + q) * N + col] = (f16)v;
      }
    }
  }
}

// ---------------- RoPE: qkv[S][3*HID] -> qh/kh [H][S][DP] (zero-padded) ----------------
__global__ __launch_bounds__(256) void rope_kernel(const f16* __restrict__ qkvb,
                                                   const float* __restrict__ rpe,
                                                   f16* __restrict__ qh,
                                                   f16* __restrict__ kh) {
  int t = blockIdx.x * 256 + threadIdx.x;
  if (t >= SEQ * NH * 40) return;
  const int d = t % 40;
  const int h = (t / 40) % NH;
  const int s = t / (40 * NH);
  const float f = rpe[s * 40 + d];
  const float cs = cosf(f), sn = sinf(f);
  const size_t base = (size_t)s * (3 * HIDN) + h * HD;
  const float q0 = (float)qkvb[base + d];
  const float q1 = (float)qkvb[base + 40 + d];
  const float k0 = (float)qkvb[base + HIDN + d];
  const float k1 = (float)qkvb[base + HIDN + 40 + d];
  const size_t ob = ((size_t)h * SEQ + s) * DP;
  qh[ob + d]      = (f16)(q0 * cs - q1 * sn);
  qh[ob + 40 + d] = (f16)(q1 * cs + q0 * sn);
  kh[ob + d]      = (f16)(k0 * cs - k1 * sn);
  kh[ob + 40 + d] = (f16)(k1 * cs + k0 * sn);
  if (d < DP - HD) { qh[ob + HD + d] = (f16)0.f; kh[ob + HD + d] = (f16)0.f; }
}

// ---------------- V transpose: qkv v-part -> vt[H][HD][SEQ] ----------------
__global__ __launch_bounds__(256) void vtrans_kernel(const f16* __restrict__ qkvb,
                                                     f16* __restrict__ vt) {
  __shared__ f16 tile[HD][65];
  const int h = blockIdx.y;
  const int s0 = blockIdx.x * 64;
  for (int idx = threadIdx.x; idx < 64 * HD; idx += 256) {
    const int sr = idx / HD, d = idx % HD;
    tile[d][sr] = qkvb[(size_t)(s0 + sr) * (3 * HIDN) + 2 * HIDN + h * HD + d];
  }
  __syncthreads();
  for (int idx = threadIdx.x; idx < HD * 64; idx += 256) {
    const int d = idx >> 6, sc = idx & 63;
    vt[((size_t)h * HD + d) * SEQ + s0 + sc] = tile[d][sc];
  }
}

// ---------------- Flash attention over block-diagonal segments ----------------
// grid (SEQ/64, NH); block 256 = 4 waves x 16 q-rows; kv tiles of 32.
__global__ __launch_bounds__(256) void attn_kernel(const f16* __restrict__ qh,
                                                   const f16* __restrict__ kh,
                                                   const f16* __restrict__ vt,
                                                   const int* __restrict__ cu,
                                                   f16* __restrict__ ao) {
  __shared__ __align__(16) f16 Ks[32 * KROWS];
  __shared__ __align__(16) f16 Vs[HD * VROWS];
  __shared__ __align__(16) f16 Ps[4][16 * PROWS];
  const int tid = threadIdx.x, w = tid >> 6, l = tid & 63;
  const int h = blockIdx.y;
  const int row0 = blockIdx.x * 64;
  int seg = 0;
  while (cu[seg + 1] <= row0) seg++;
  const int kvb = cu[seg], kve = cu[seg + 1];

  const int fr = l & 15, fg = (l >> 4) * 8;
  const f16* qbase = qh + ((size_t)h * SEQ + row0 + w * 16 + fr) * DP + fg;
  f16x8 aq[3];
#pragma unroll
  for (int kk = 0; kk < 3; kk++) aq[kk] = *(const f16x8*)(qbase + kk * 32);

  float m[4], lsum[4];
  f32x4 o[5] = {};
#pragma unroll
  for (int j = 0; j < 4; j++) { m[j] = -1e30f; lsum[j] = 0.f; }

  const float SCL = 0.1118033988749895f * 1.4426950408889634f;  // 1/sqrt(80) * log2(e)

  for (int kv0 = kvb; kv0 < kve; kv0 += 32) {
    __syncthreads();
    {   // stage K tile [32][96] (384 chunks) + V^T tile [80][32] (320 chunks)
      int c = tid, kr = c / 12, kg = c % 12;
      *(uint4*)(Ks + kr * KROWS + kg * 8) =
          *(const uint4*)(kh + ((size_t)h * SEQ + kv0 + kr) * DP + kg * 8);
      if (tid < 128) {
        c = 256 + tid; kr = c / 12; kg = c % 12;
        *(uint4*)(Ks + kr * KROWS + kg * 8) =
            *(const uint4*)(kh + ((size_t)h * SEQ + kv0 + kr) * DP + kg * 8);
      }
      int vr = tid >> 2, vg = tid & 3;
      *(uint4*)(Vs + vr * VROWS + vg * 8) =
          *(const uint4*)(vt + ((size_t)h * HD + vr) * SEQ + kv0 + vg * 8);
      if (tid < 64) {
        vr = (256 + tid) >> 2;
        *(uint4*)(Vs + vr * VROWS + vg * 8) =
            *(const uint4*)(vt + ((size_t)h * HD + vr) * SEQ + kv0 + vg * 8);
      }
    }
    __syncthreads();

    // QK^T: S tile 16q x 32kv, K=96 (zero-padded)
    f32x4 s0 = {0.f, 0.f, 0.f, 0.f}, s1 = {0.f, 0.f, 0.f, 0.f};
#pragma unroll
    for (int kk = 0; kk < 3; kk++) {
      f16x8 b0 = *(const f16x8*)(Ks + fr * KROWS + kk * 32 + fg);
      f16x8 b1 = *(const f16x8*)(Ks + (16 + fr) * KROWS + kk * 32 + fg);
      s0 = __builtin_amdgcn_mfma_f32_16x16x32_f16(aq[kk], b0, s0, 0, 0, 0);
      s1 = __builtin_amdgcn_mfma_f32_16x16x32_f16(aq[kk], b1, s1, 0, 0, 0);
    }

    // online softmax: row q lives in 16 lanes of group (l>>4); regs = 4 rows
    float alpha[4];
    f16* pb = &Ps[w][0];
#pragma unroll
    for (int j = 0; j < 4; j++) {
      float t0 = s0[j] * SCL, t1 = s1[j] * SCL;
      float mx = fmaxf(t0, t1);
      mx = fmaxf(mx, __shfl_xor(mx, 1));
      mx = fmaxf(mx, __shfl_xor(mx, 2));
      mx = fmaxf(mx, __shfl_xor(mx, 4));
      mx = fmaxf(mx, __shfl_xor(mx, 8));
      const float mn = fmaxf(m[j], mx);
      alpha[j] = exp2f(m[j] - mn);
      m[j] = mn;
      const float p0 = exp2f(t0 - mn);
      const float p1 = exp2f(t1 - mn);
      lsum[j] = lsum[j] * alpha[j] + p0 + p1;  // per-lane partial, reduced at end
      const int prow = (l >> 4) * 4 + j;
      pb[prow * PROWS + fr]      = (f16)p0;
      pb[prow * PROWS + 16 + fr] = (f16)p1;
    }
#pragma unroll
    for (int dt = 0; dt < 5; dt++)
#pragma unroll
      for (int j = 0; j < 4; j++) o[dt][j] *= alpha[j];

    // PV: O[16q][80d] += P[16q][32kv] * V[32kv][80d]
    f16x8 pa = *(const f16x8*)(pb + fr * PROWS + fg);
#pragma unroll
    for (int dt = 0; dt < 5; dt++) {
      f16x8 bv = *(const f16x8*)(Vs + (dt * 16 + fr) * VROWS + fg);
      o[dt] = __builtin_amdgcn_mfma_f32_16x16x32_f16(pa, bv, o[dt], 0, 0, 0);
    }
  }

#pragma unroll
  for (int j = 0; j < 4; j++) {
    float ssum = lsum[j];
    ssum += __shfl_xor(ssum, 1);
    ssum += __shfl_xor(ssum, 2);
    ssum += __shfl_xor(ssum, 4);
    ssum += __shfl_xor(ssum, 8);
    lsum[j] = 1.0f / ssum;
  }
  const int orow = row0 + w * 16 + (l >> 4) * 4;
#pragma unroll
  for (int dt = 0; dt < 5; dt++)
#pragma unroll
    for (int j = 0; j < 4; j++)
      ao[(size_t)(orow + j) * HIDN + h * HD + dt * 16 + fr] = (f16)(o[dt][j] * lsum[j]);
}

extern "C" void kernel_launch(void* const* d_in, const int* in_sizes, int n_in,
                              void* d_out, int out_size, void* d_ws, size_t ws_size,
                              hipStream_t stream) {
  const float* x      = (const float*)d_in[0];
  const int*   cu     = (const int*)d_in[1];
  const float* rpe    = (const float*)d_in[2];
  const float* qkv_w  = (const float*)d_in[3];
  const float* qkv_b  = (const float*)d_in[4];
  const float* proj_w = (const float*)d_in[5];
  const float* proj_b = (const float*)d_in[6];

  char* ws = (char*)d_ws;
  f16* xb    = (f16*)(ws);              // [4096][1280]            10.5 MB
  f16* wqkv  = (f16*)(ws + 10485760);   // [3840][1280]             9.8 MB
  f16* wproj = (f16*)(ws + 20316160);   // [1280][1280]             3.3 MB
  f16* qkvb  = (f16*)(ws + 23592960);   // [4096][3840]            31.5 MB
  f16* qh    = (f16*)(ws + 55050240);   // [16][4096][96]          12.6 MB
  f16* kh    = (f16*)(ws + 67633152);   // [16][4096][96]          12.6 MB
  f16* vt    = (f16*)(ws + 80216064);   // [16][80][4096]          10.5 MB  (end 90.7 MB)
  f16* ao    = xb;                      // reuse (xb dead after GEMM1)

  cvt_kernel<<<2560, 256, 0, stream>>>(x, xb, SEQ * HIDN);
  cvt_kernel<<<2400, 256, 0, stream>>>(qkv_w, wqkv, 3 * HIDN * HIDN);
  cvt_kernel<<<800, 256, 0, stream>>>(proj_w, wproj, HIDN * HIDN);

  gemm_bt<0><<<dim3(3 * HIDN / 128, SEQ / 128), 256, 0, stream>>>(
      xb, wqkv, qkv_b, qkvb, SEQ, 3 * HIDN, HIDN);

  rope_kernel<<<(SEQ * NH * 40) / 256, 256, 0, stream>>>(qkvb, rpe, qh, kh);
  vtrans_kernel<<<dim3(SEQ / 64, NH), 256, 0, stream>>>(qkvb, vt);

  attn_kernel<<<dim3(SEQ / 64, NH), 256, 0, stream>>>(qh, kh, vt, cu, ao);

  gemm_bt<1><<<dim3(HIDN / 128, SEQ / 128), 256, 0, stream>>>(
      ao, wproj, proj_b, d_out, SEQ, HIDN, HIDN);
}

// Round 2
// 198.963 us; speedup vs baseline: 1.1226x; 1.1226x over previous
//
#include <hip/hip_runtime.h>

typedef _Float16 f16;
typedef __attribute__((ext_vector_type(8))) _Float16 f16x8;
typedef __attribute__((ext_vector_type(4))) float f32x4;

#define SEQ   4096
#define NH    16
#define HD    80
#define HIDN  1280
#define DP    96      // padded head dim (3 x K=32 MFMA steps)
#define KROWS 104     // K-tile LDS row stride (208B = 13 chunks -> 2-way bank alias)
#define VROWS 56      // V-tile LDS row stride (112B = 7 chunks  -> 2-way)
#define PROWS 56      // P-buffer row stride

__device__ __forceinline__ void gload16(const void* g, void* l) {
  __builtin_amdgcn_global_load_lds(
      (const __attribute__((address_space(1))) unsigned int*)g,
      (__attribute__((address_space(3))) unsigned int*)l, 16, 0, 0);
}

// ---------------- f32 -> f16 convert (n % 8 == 0) ----------------
__global__ __launch_bounds__(256) void cvt_kernel(const float* __restrict__ s,
                                                  f16* __restrict__ d, int n) {
  int base = (blockIdx.x * 256 + threadIdx.x) * 8;
  if (base >= n) return;
  f32x4 v0 = *(const f32x4*)(s + base);
  f32x4 v1 = *(const f32x4*)(s + base + 4);
  f16x8 o;
#pragma unroll
  for (int j = 0; j < 4; j++) { o[j] = (f16)v0[j]; o[4 + j] = (f16)v1[j]; }
  *(f16x8*)(d + base) = o;
}

// ---------------- GEMM: C[M][N] = A[M][K] * B[N][K]^T + bias ----------------
template<int OUT_F32>
__global__ __launch_bounds__(256) void gemm_bt(const f16* __restrict__ A,
                                               const f16* __restrict__ B,
                                               const float* __restrict__ bias,
                                               void* __restrict__ C,
                                               int M, int N, int K) {
  __shared__ __align__(16) f16 As[128 * 32];
  __shared__ __align__(16) f16 Bs[128 * 32];
  const int tid = threadIdx.x;
  const int w = tid >> 6, l = tid & 63;
  const int m0 = blockIdx.y * 128, n0 = blockIdx.x * 128;
  const int wm = (w >> 1) * 64, wn = (w & 1) * 64;

  const int c0 = w * 64 + l;
  const int c1 = (4 + w) * 64 + l;
  const size_t a0 = (size_t)(m0 + (c0 >> 2)) * K + (c0 & 3) * 8;
  const size_t a1 = (size_t)(m0 + (c1 >> 2)) * K + (c1 & 3) * 8;
  const size_t b0 = (size_t)(n0 + (c0 >> 2)) * K + (c0 & 3) * 8;
  const size_t b1 = (size_t)(n0 + (c1 >> 2)) * K + (c1 & 3) * 8;

  f32x4 acc[4][4] = {};
  const int fr = l & 15, fg = (l >> 4) * 8;

  for (int k0 = 0; k0 < K; k0 += 32) {
    if (k0) __syncthreads();
    gload16(A + a0 + k0, As + w * 512);
    gload16(A + a1 + k0, As + (4 + w) * 512);
    gload16(B + b0 + k0, Bs + w * 512);
    gload16(B + b1 + k0, Bs + (4 + w) * 512);
    __syncthreads();
    f16x8 af[4], bf[4];
#pragma unroll
    for (int i = 0; i < 4; i++)
      af[i] = *(const f16x8*)(As + (wm + i * 16 + fr) * 32 + fg);
#pragma unroll
    for (int j = 0; j < 4; j++)
      bf[j] = *(const f16x8*)(Bs + (wn + j * 16 + fr) * 32 + fg);
#pragma unroll
    for (int i = 0; i < 4; i++)
#pragma unroll
      for (int j = 0; j < 4; j++)
        acc[i][j] = __builtin_amdgcn_mfma_f32_16x16x32_f16(af[i], bf[j], acc[i][j], 0, 0, 0);
  }

  const int q4 = (l >> 4) * 4;
#pragma unroll
  for (int i = 0; i < 4; i++) {
    const int row = m0 + wm + i * 16 + q4;
#pragma unroll
    for (int j = 0; j < 4; j++) {
      const int col = n0 + wn + j * 16 + fr;
      const float bv = bias[col];
#pragma unroll
      for (int q = 0; q < 4; q++) {
        float v = acc[i][j][q] + bv;
        if (OUT_F32) ((float*)C)[(size_t)(row + q) * N + col] = v;
        else         ((f16*)C)[(size_t)(row + q) * N + col] = (f16)v;
      }
    }
  }
}

// ---------------- RoPE: qkv[S][3*HID] -> qh/kh [H][S][DP]; q pre-scaled ----------------
__global__ __launch_bounds__(256) void rope_kernel(const f16* __restrict__ qkvb,
                                                   const float* __restrict__ rpe,
                                                   f16* __restrict__ qh,
                                                   f16* __restrict__ kh) {
  const float SCLT = 0.1118033988749895f * 1.4426950408889634f;  // 1/sqrt(80)*log2(e)
  int t = blockIdx.x * 256 + threadIdx.x;
  if (t >= SEQ * NH * 40) return;
  const int d = t % 40;
  const int h = (t / 40) % NH;
  const int s = t / (40 * NH);
  const float f = rpe[s * 40 + d];
  float sn, cs;
  __sincosf(f, &sn, &cs);
  const size_t base = (size_t)s * (3 * HIDN) + h * HD;
  const float q0 = (float)qkvb[base + d];
  const float q1 = (float)qkvb[base + 40 + d];
  const float k0 = (float)qkvb[base + HIDN + d];
  const float k1 = (float)qkvb[base + HIDN + 40 + d];
  const size_t ob = ((size_t)h * SEQ + s) * DP;
  qh[ob + d]      = (f16)((q0 * cs - q1 * sn) * SCLT);
  qh[ob + 40 + d] = (f16)((q1 * cs + q0 * sn) * SCLT);
  kh[ob + d]      = (f16)(k0 * cs - k1 * sn);
  kh[ob + 40 + d] = (f16)(k1 * cs + k0 * sn);
  if (d < DP - HD) { qh[ob + HD + d] = (f16)0.f; kh[ob + HD + d] = (f16)0.f; }
}

// ---------------- V transpose: qkv v-part -> vt[H][HD][SEQ] ----------------
__global__ __launch_bounds__(256) void vtrans_kernel(const f16* __restrict__ qkvb,
                                                     f16* __restrict__ vt) {
  __shared__ f16 tile[HD][65];
  const int h = blockIdx.y;
  const int s0 = blockIdx.x * 64;
  for (int idx = threadIdx.x; idx < 64 * HD; idx += 256) {
    const int sr = idx / HD, d = idx % HD;
    tile[d][sr] = qkvb[(size_t)(s0 + sr) * (3 * HIDN) + 2 * HIDN + h * HD + d];
  }
  __syncthreads();
  for (int idx = threadIdx.x; idx < HD * 64; idx += 256) {
    const int d = idx >> 6, sc = idx & 63;
    vt[((size_t)h * HD + d) * SEQ + s0 + sc] = tile[d][sc];
  }
}

// ---------------- Flash attention over block-diagonal segments ----------------
// grid (SEQ/128, NH); block 256 = 4 waves; each wave owns 32 q-rows (2 subtiles of 16).
// kv tiles of 32, async-staged (load regs during compute, write LDS after barrier).
__global__ __launch_bounds__(256) void attn_kernel(const f16* __restrict__ qh,
                                                   const f16* __restrict__ kh,
                                                   const f16* __restrict__ vt,
                                                   const int* __restrict__ cu,
                                                   f16* __restrict__ ao) {
  __shared__ __align__(16) f16 Ks[32 * KROWS];
  __shared__ __align__(16) f16 Vs[HD * VROWS];
  __shared__ __align__(16) f16 Ps[4][32 * PROWS];
  const int tid = threadIdx.x, w = tid >> 6, l = tid & 63;
  const int h = blockIdx.y;
  const int row0 = blockIdx.x * 128;
  int seg = 0;
  while (cu[seg + 1] <= row0) seg++;
  const int kvb = cu[seg], kve = cu[seg + 1];

  const int fr = l & 15, fg = (l >> 4) * 8;

  // Q fragments for both subtiles (q pre-scaled by 1/sqrt(80)*log2e)
  const f16* qb = qh + ((size_t)h * SEQ + row0 + w * 32 + fr) * DP + fg;
  f16x8 aq0[3], aq1[3];
#pragma unroll
  for (int kk = 0; kk < 3; kk++) {
    aq0[kk] = *(const f16x8*)(qb + kk * 32);
    aq1[kk] = *(const f16x8*)(qb + 16 * DP + kk * 32);
  }

  // staging addresses (K: 384 chunks, V: 320 chunks, 256 threads)
  const int kr0 = tid / 12, kg0 = tid % 12;
  const int kr1 = (256 + tid) / 12, kg1 = (256 + tid) % 12;
  const int vr0 = tid >> 2, vg = tid & 3;
  const int vr1 = (256 + tid) >> 2;
  const f16* kp0 = kh + ((size_t)h * SEQ + kvb + kr0) * DP + kg0 * 8;
  const f16* kp1 = kh + ((size_t)h * SEQ + kvb + kr1) * DP + kg1 * 8;
  const f16* vp0 = vt + ((size_t)h * HD + vr0) * SEQ + kvb + vg * 8;
  const f16* vp1 = vt + ((size_t)h * HD + vr1) * SEQ + kvb + vg * 8;
  f16* kl0 = Ks + kr0 * KROWS + kg0 * 8;
  f16* kl1 = Ks + kr1 * KROWS + kg1 * 8;
  f16* vl0 = Vs + vr0 * VROWS + vg * 8;
  f16* vl1 = Vs + vr1 * VROWS + vg * 8;

  uint4 rk0, rk1, rv0, rv1;
  rk0 = *(const uint4*)kp0;
  if (tid < 128) rk1 = *(const uint4*)kp1;
  rv0 = *(const uint4*)vp0;
  if (tid < 64)  rv1 = *(const uint4*)vp1;

  float m = -1e30f;
  float ls0[4] = {0.f, 0.f, 0.f, 0.f}, ls1[4] = {0.f, 0.f, 0.f, 0.f};
  f32x4 o0[5] = {}, o1[5] = {};
  f16* pb = &Ps[w][0];

  for (int kv0 = kvb; kv0 < kve; kv0 += 32) {
    __syncthreads();                 // everyone done reading previous tile
    *(uint4*)kl0 = rk0;
    if (tid < 128) *(uint4*)kl1 = rk1;
    *(uint4*)vl0 = rv0;
    if (tid < 64)  *(uint4*)vl1 = rv1;
    __syncthreads();                 // tile visible to all waves

    // prefetch next tile into regs; latency hides under compute below
    const int nxt = kv0 + 32 - kvb;
    if (kv0 + 32 < kve) {
      rk0 = *(const uint4*)(kp0 + (size_t)nxt * DP);
      if (tid < 128) rk1 = *(const uint4*)(kp1 + (size_t)nxt * DP);
      rv0 = *(const uint4*)(vp0 + nxt);
      if (tid < 64)  rv1 = *(const uint4*)(vp1 + nxt);
    }

    // QK^T: two 16q x 32kv S-tiles, K-frags shared
    f32x4 sA0 = {0.f,0.f,0.f,0.f}, sA1 = {0.f,0.f,0.f,0.f};
    f32x4 sB0 = {0.f,0.f,0.f,0.f}, sB1 = {0.f,0.f,0.f,0.f};
#pragma unroll
    for (int kk = 0; kk < 3; kk++) {
      f16x8 b0 = *(const f16x8*)(Ks + fr * KROWS + kk * 32 + fg);
      f16x8 b1 = *(const f16x8*)(Ks + (16 + fr) * KROWS + kk * 32 + fg);
      sA0 = __builtin_amdgcn_mfma_f32_16x16x32_f16(aq0[kk], b0, sA0, 0, 0, 0);
      sA1 = __builtin_amdgcn_mfma_f32_16x16x32_f16(aq0[kk], b1, sA1, 0, 0, 0);
      sB0 = __builtin_amdgcn_mfma_f32_16x16x32_f16(aq1[kk], b0, sB0, 0, 0, 0);
      sB1 = __builtin_amdgcn_mfma_f32_16x16x32_f16(aq1[kk], b1, sB1, 0, 0, 0);
    }

    // wave-uniform tile max (scores already in log2 units)
    float tmax = sA0[0];
#pragma unroll
    for (int j = 0; j < 4; j++) {
      tmax = fmaxf(tmax, fmaxf(sA0[j], sA1[j]));
      tmax = fmaxf(tmax, fmaxf(sB0[j], sB1[j]));
    }
    tmax = fmaxf(tmax, __shfl_xor(tmax, 1));
    tmax = fmaxf(tmax, __shfl_xor(tmax, 2));
    tmax = fmaxf(tmax, __shfl_xor(tmax, 4));
    tmax = fmaxf(tmax, __shfl_xor(tmax, 8));
    tmax = fmaxf(tmax, __shfl_xor(tmax, 16));
    tmax = fmaxf(tmax, __shfl_xor(tmax, 32));

    if (tmax > m + 8.f) {            // deferred rescale (T13, THR=8): rare
      const float a = exp2f(m - tmax);
      m = tmax;
#pragma unroll
      for (int j = 0; j < 4; j++) { ls0[j] *= a; ls1[j] *= a; }
#pragma unroll
      for (int dt = 0; dt < 5; dt++)
#pragma unroll
        for (int j = 0; j < 4; j++) { o0[dt][j] *= a; o1[dt][j] *= a; }
    }

    // P = exp2(S - m), bounded by 2^8; accumulate per-lane partial row sums
#pragma unroll
    for (int j = 0; j < 4; j++) {
      const float pA0 = exp2f(sA0[j] - m), pA1 = exp2f(sA1[j] - m);
      const float pB0 = exp2f(sB0[j] - m), pB1 = exp2f(sB1[j] - m);
      ls0[j] += pA0 + pA1;
      ls1[j] += pB0 + pB1;
      const int pr = (l >> 4) * 4 + j;
      pb[pr * PROWS + fr]             = (f16)pA0;
      pb[pr * PROWS + 16 + fr]        = (f16)pA1;
      pb[(16 + pr) * PROWS + fr]      = (f16)pB0;
      pb[(16 + pr) * PROWS + 16 + fr] = (f16)pB1;
    }

    // PV: V-frags shared across both subtiles
    f16x8 paA = *(const f16x8*)(pb + fr * PROWS + fg);
    f16x8 paB = *(const f16x8*)(pb + (16 + fr) * PROWS + fg);
#pragma unroll
    for (int dt = 0; dt < 5; dt++) {
      f16x8 bv = *(const f16x8*)(Vs + (dt * 16 + fr) * VROWS + fg);
      o0[dt] = __builtin_amdgcn_mfma_f32_16x16x32_f16(paA, bv, o0[dt], 0, 0, 0);
      o1[dt] = __builtin_amdgcn_mfma_f32_16x16x32_f16(paB, bv, o1[dt], 0, 0, 0);
    }
  }

#pragma unroll
  for (int j = 0; j < 4; j++) {
    float sa = ls0[j], sb = ls1[j];
    sa += __shfl_xor(sa, 1); sb += __shfl_xor(sb, 1);
    sa += __shfl_xor(sa, 2); sb += __shfl_xor(sb, 2);
    sa += __shfl_xor(sa, 4); sb += __shfl_xor(sb, 4);
    sa += __shfl_xor(sa, 8); sb += __shfl_xor(sb, 8);
    ls0[j] = 1.0f / sa;
    ls1[j] = 1.0f / sb;
  }
  const int orow = row0 + w * 32 + (l >> 4) * 4;
#pragma unroll
  for (int dt = 0; dt < 5; dt++)
#pragma unroll
    for (int j = 0; j < 4; j++) {
      ao[(size_t)(orow + j) * HIDN + h * HD + dt * 16 + fr]      = (f16)(o0[dt][j] * ls0[j]);
      ao[(size_t)(orow + 16 + j) * HIDN + h * HD + dt * 16 + fr] = (f16)(o1[dt][j] * ls1[j]);
    }
}

extern "C" void kernel_launch(void* const* d_in, const int* in_sizes, int n_in,
                              void* d_out, int out_size, void* d_ws, size_t ws_size,
                              hipStream_t stream) {
  const float* x      = (const float*)d_in[0];
  const int*   cu     = (const int*)d_in[1];
  const float* rpe    = (const float*)d_in[2];
  const float* qkv_w  = (const float*)d_in[3];
  const float* qkv_b  = (const float*)d_in[4];
  const float* proj_w = (const float*)d_in[5];
  const float* proj_b = (const float*)d_in[6];

  char* ws = (char*)d_ws;
  f16* xb    = (f16*)(ws);              // [4096][1280]            10.5 MB
  f16* wqkv  = (f16*)(ws + 10485760);   // [3840][1280]             9.8 MB
  f16* wproj = (f16*)(ws + 20316160);   // [1280][1280]             3.3 MB
  f16* qkvb  = (f16*)(ws + 23592960);   // [4096][3840]            31.5 MB
  f16* qh    = (f16*)(ws + 55050240);   // [16][4096][96]          12.6 MB
  f16* kh    = (f16*)(ws + 67633152);   // [16][4096][96]          12.6 MB
  f16* vt    = (f16*)(ws + 80216064);   // [16][80][4096]          10.5 MB
  f16* ao    = xb;                      // reuse (xb dead after GEMM1)

  cvt_kernel<<<2560, 256, 0, stream>>>(x, xb, SEQ * HIDN);
  cvt_kernel<<<2400, 256, 0, stream>>>(qkv_w, wqkv, 3 * HIDN * HIDN);
  cvt_kernel<<<800, 256, 0, stream>>>(proj_w, wproj, HIDN * HIDN);

  gemm_bt<0><<<dim3(3 * HIDN / 128, SEQ / 128), 256, 0, stream>>>(
      xb, wqkv, qkv_b, qkvb, SEQ, 3 * HIDN, HIDN);

  rope_kernel<<<(SEQ * NH * 40) / 256, 256, 0, stream>>>(qkvb, rpe, qh, kh);
  vtrans_kernel<<<dim3(SEQ / 64, NH), 256, 0, stream>>>(qkvb, vt);

  attn_kernel<<<dim3(SEQ / 128, NH), 256, 0, stream>>>(qh, kh, vt, cu, ao);

  gemm_bt<1><<<dim3(HIDN / 128, SEQ / 128), 256, 0, stream>>>(
      ao, wproj, proj_b, d_out, SEQ, HIDN, HIDN);
}

// Round 3
// 171.948 us; speedup vs baseline: 1.2990x; 1.1571x over previous
//
#include <hip/hip_runtime.h>

typedef _Float16 f16;
typedef __attribute__((ext_vector_type(8))) _Float16 f16x8;
typedef __attribute__((ext_vector_type(4))) float f32x4;

#define SEQ   4096
#define NH    16
#define HD    80
#define HIDN  1280
#define DP    96
#define KROWS 104
#define VROWS 56
#define PROWS 56

// 8-phase GEMM constants (QKV: M=4096, N=3840, K=1280)
#define KQ   1280
#define NQ   3840
#define NIT  10      // K / 128

__device__ __forceinline__ void gload16(const void* g, void* l) {
  __builtin_amdgcn_global_load_lds(
      (const __attribute__((address_space(1))) unsigned int*)g,
      (__attribute__((address_space(3))) unsigned int*)l, 16, 0, 0);
}

#define BAR() __builtin_amdgcn_s_barrier()
#define VMCNT(n) do { asm volatile("s_waitcnt vmcnt(" #n ")" ::: "memory"); \
                      __builtin_amdgcn_sched_barrier(0); } while (0)
// stage one half-tile (128 rows x 64 K) = 2 x gload_lds per thread
#define STG(Lb, g, buf, h, kt)                                                  \
  do {                                                                          \
    gload16((g) + (size_t)((h) * 128) * KQ + (kt) * 64,                         \
            (Lb) + (buf) * 16384 + ((h) * 128) * 64 + w * 512);                 \
    gload16((g) + (size_t)((h) * 128 + 64) * KQ + (kt) * 64,                    \
            (Lb) + (buf) * 16384 + ((h) * 128 + 64) * 64 + w * 512);            \
  } while (0)
#define MFQ(IOFF, JOFF, BB)                                                     \
  do {                                                                          \
    __builtin_amdgcn_s_setprio(1);                                              \
    _Pragma("unroll")                                                           \
    for (int i_ = 0; i_ < 4; i_++)                                              \
      _Pragma("unroll")                                                         \
      for (int j_ = 0; j_ < 2; j_++)                                            \
        _Pragma("unroll")                                                       \
        for (int s_ = 0; s_ < 2; s_++)                                          \
          acc[i_ + IOFF][j_ + JOFF] = __builtin_amdgcn_mfma_f32_16x16x32_f16(   \
              a[i_][s_], BB[j_][s_], acc[i_ + IOFF][j_ + JOFF], 0, 0, 0);       \
    __builtin_amdgcn_s_setprio(0);                                              \
  } while (0)

// ---------------- f32 -> f16 convert (n % 8 == 0) ----------------
__global__ __launch_bounds__(256) void cvt_kernel(const float* __restrict__ s,
                                                  f16* __restrict__ d, int n) {
  int base = (blockIdx.x * 256 + threadIdx.x) * 8;
  if (base >= n) return;
  f32x4 v0 = *(const f32x4*)(s + base);
  f32x4 v1 = *(const f32x4*)(s + base + 4);
  f16x8 o;
#pragma unroll
  for (int j = 0; j < 4; j++) { o[j] = (f16)v0[j]; o[4 + j] = (f16)v1[j]; }
  *(f16x8*)(d + base) = o;
}

// ---------------- 8-phase 256^2 GEMM: C[4096][3840] = A * B^T + bias (f16 out) ----
// 512 thr = 8 waves (2Mx4N), BK=64, 2 K-tiles/iter, T2 chunk-swizzle, counted vmcnt.
__global__ __launch_bounds__(512, 2) void qkv_gemm8(const f16* __restrict__ A,
                                                    const f16* __restrict__ B,
                                                    const float* __restrict__ bias,
                                                    f16* __restrict__ C) {
  __shared__ __align__(16) f16 LA[2 * 16384];
  __shared__ __align__(16) f16 LB[2 * 16384];
  const int tid = threadIdx.x, w = tid >> 6, l = tid & 63;
  const int bid = (blockIdx.x & 7) * 30 + (blockIdx.x >> 3);  // XCD swizzle, 240 = 8*30
  const int bx = bid % 15, by = bid / 15;
  const int m0 = by * 256, n0 = bx * 256;
  const int wm = (w >> 2) * 128, wn = (w & 3) * 64;
  const int fr = l & 15, fq = l >> 4;
  const int rx = fr & 7;
  const int cA0 = (fq ^ rx) * 8;        // swizzled chunk offset, k-step 0
  const int cA1 = ((4 + fq) ^ rx) * 8;  // k-step 1

  // staging source: thread covers chunk (row = w*8 + l>>3, chunk col swizzled)
  const int srow = w * 8 + (l >> 3);
  const int scol = ((l & 7) ^ (l >> 3)) * 8;
  const f16* gA = A + (size_t)(m0 + srow) * KQ + scol;
  const f16* gB = B + (size_t)(n0 + srow) * KQ + scol;

  f32x4 acc[8][4] = {};
  f16x8 a[4][2], b0[2][2], b1[2][2];

  // prologue: K-tile 0 (buf0) fully + Bh0/Bh1 of K-tile 1 (buf1)
  STG(LA, gA, 0, 0, 0); STG(LA, gA, 0, 1, 0);
  STG(LB, gB, 0, 0, 0); STG(LB, gB, 0, 1, 0);
  STG(LB, gB, 1, 0, 1); STG(LB, gB, 1, 1, 1);
  VMCNT(4);
  BAR();

  for (int it = 0; it < NIT; ++it) {
    const int t = 2 * it;
    const bool lastit = (it == NIT - 1);

    // phase 1: ds aL,bL (buf0) | stage Ah0(t+1)->buf1 | MFMA q(0,0)
#pragma unroll
    for (int i = 0; i < 4; i++) {
      a[i][0] = *(const f16x8*)(LA + (wm + i * 16 + fr) * 64 + cA0);
      a[i][1] = *(const f16x8*)(LA + (wm + i * 16 + fr) * 64 + cA1);
    }
#pragma unroll
    for (int j = 0; j < 2; j++) {
      b0[j][0] = *(const f16x8*)(LB + (wn + j * 16 + fr) * 64 + cA0);
      b0[j][1] = *(const f16x8*)(LB + (wn + j * 16 + fr) * 64 + cA1);
    }
    STG(LA, gA, 1, 0, t + 1);
    BAR(); MFQ(0, 0, b0); BAR();

    // phase 2: ds bH (buf0) | stage Ah1(t+1) | MFMA q(0,2)
#pragma unroll
    for (int j = 0; j < 2; j++) {
      b1[j][0] = *(const f16x8*)(LB + (wn + 32 + j * 16 + fr) * 64 + cA0);
      b1[j][1] = *(const f16x8*)(LB + (wn + 32 + j * 16 + fr) * 64 + cA1);
    }
    STG(LA, gA, 1, 1, t + 1);
    BAR(); MFQ(0, 2, b1); BAR();

    // phase 3: ds aH (buf0) | stage Bh0(t+2)->buf0 (B regions free after ph2) | MFMA q(4,0)
#pragma unroll
    for (int i = 0; i < 4; i++) {
      a[i][0] = *(const f16x8*)(LA + (wm + 64 + i * 16 + fr) * 64 + cA0);
      a[i][1] = *(const f16x8*)(LA + (wm + 64 + i * 16 + fr) * 64 + cA1);
    }
    if (!lastit) { STG(LB, gB, 0, 0, t + 2); }
    BAR(); MFQ(4, 0, b0); BAR();

    // phase 4: stage Bh1(t+2) | vmcnt guard for buf1 reads | MFMA q(4,2)
    if (!lastit) { STG(LB, gB, 0, 1, t + 2); VMCNT(4); }
    else         { VMCNT(0); }
    BAR(); MFQ(4, 2, b1); BAR();

    // phase 5: ds aL,bL (buf1) | stage Ah0(t+2)->buf0 (A free after ph3) | MFMA q(0,0)
#pragma unroll
    for (int i = 0; i < 4; i++) {
      a[i][0] = *(const f16x8*)(LA + 16384 + (wm + i * 16 + fr) * 64 + cA0);
      a[i][1] = *(const f16x8*)(LA + 16384 + (wm + i * 16 + fr) * 64 + cA1);
    }
#pragma unroll
    for (int j = 0; j < 2; j++) {
      b0[j][0] = *(const f16x8*)(LB + 16384 + (wn + j * 16 + fr) * 64 + cA0);
      b0[j][1] = *(const f16x8*)(LB + 16384 + (wn + j * 16 + fr) * 64 + cA1);
    }
    if (!lastit) { STG(LA, gA, 0, 0, t + 2); }
    BAR(); MFQ(0, 0, b0); BAR();

    // phase 6: ds bH (buf1) | stage Ah1(t+2) | MFMA q(0,2)
#pragma unroll
    for (int j = 0; j < 2; j++) {
      b1[j][0] = *(const f16x8*)(LB + 16384 + (wn + 32 + j * 16 + fr) * 64 + cA0);
      b1[j][1] = *(const f16x8*)(LB + 16384 + (wn + 32 + j * 16 + fr) * 64 + cA1);
    }
    if (!lastit) { STG(LA, gA, 0, 1, t + 2); }
    BAR(); MFQ(0, 2, b1); BAR();

    // phase 7: ds aH (buf1) | stage Bh0(t+3)->buf1 (B of buf1 free after ph6) | MFMA q(4,0)
#pragma unroll
    for (int i = 0; i < 4; i++) {
      a[i][0] = *(const f16x8*)(LA + 16384 + (wm + 64 + i * 16 + fr) * 64 + cA0);
      a[i][1] = *(const f16x8*)(LA + 16384 + (wm + 64 + i * 16 + fr) * 64 + cA1);
    }
    if (!lastit) { STG(LB, gB, 1, 0, t + 3); }
    BAR(); MFQ(4, 0, b0); BAR();

    // phase 8: stage Bh1(t+3) | vmcnt guard for next iter's buf0 reads | MFMA q(4,2)
    if (!lastit) { STG(LB, gB, 1, 1, t + 3); VMCNT(4); }
    BAR(); MFQ(4, 2, b1); BAR();
  }

  // epilogue: C/D layout col=lane&15, row=(lane>>4)*4+reg
#pragma unroll
  for (int i = 0; i < 8; i++) {
    const int row = m0 + wm + i * 16 + fq * 4;
#pragma unroll
    for (int j = 0; j < 4; j++) {
      const int col = n0 + wn + j * 16 + fr;
      const float bv = bias[col];
#pragma unroll
      for (int q = 0; q < 4; q++)
        C[(size_t)(row + q) * NQ + col] = (f16)(acc[i][j][q] + bv);
    }
  }
}

// ---------------- 128^2 GEMM (kept for proj: N=1280 too small for 256^2 grid) ----
template<int OUT_F32>
__global__ __launch_bounds__(256) void gemm_bt(const f16* __restrict__ A,
                                               const f16* __restrict__ B,
                                               const float* __restrict__ bias,
                                               void* __restrict__ C,
                                               int M, int N, int K) {
  __shared__ __align__(16) f16 As[128 * 32];
  __shared__ __align__(16) f16 Bs[128 * 32];
  const int tid = threadIdx.x;
  const int w = tid >> 6, l = tid & 63;
  const int m0 = blockIdx.y * 128, n0 = blockIdx.x * 128;
  const int wm = (w >> 1) * 64, wn = (w & 1) * 64;

  const int c0 = w * 64 + l;
  const int c1 = (4 + w) * 64 + l;
  const size_t a0 = (size_t)(m0 + (c0 >> 2)) * K + (c0 & 3) * 8;
  const size_t a1 = (size_t)(m0 + (c1 >> 2)) * K + (c1 & 3) * 8;
  const size_t b0 = (size_t)(n0 + (c0 >> 2)) * K + (c0 & 3) * 8;
  const size_t b1 = (size_t)(n0 + (c1 >> 2)) * K + (c1 & 3) * 8;

  f32x4 acc[4][4] = {};
  const int fr = l & 15, fg = (l >> 4) * 8;

  for (int k0 = 0; k0 < K; k0 += 32) {
    if (k0) __syncthreads();
    gload16(A + a0 + k0, As + w * 512);
    gload16(A + a1 + k0, As + (4 + w) * 512);
    gload16(B + b0 + k0, Bs + w * 512);
    gload16(B + b1 + k0, Bs + (4 + w) * 512);
    __syncthreads();
    f16x8 af[4], bf[4];
#pragma unroll
    for (int i = 0; i < 4; i++)
      af[i] = *(const f16x8*)(As + (wm + i * 16 + fr) * 32 + fg);
#pragma unroll
    for (int j = 0; j < 4; j++)
      bf[j] = *(const f16x8*)(Bs + (wn + j * 16 + fr) * 32 + fg);
#pragma unroll
    for (int i = 0; i < 4; i++)
#pragma unroll
      for (int j = 0; j < 4; j++)
        acc[i][j] = __builtin_amdgcn_mfma_f32_16x16x32_f16(af[i], bf[j], acc[i][j], 0, 0, 0);
  }

  const int q4 = (l >> 4) * 4;
#pragma unroll
  for (int i = 0; i < 4; i++) {
    const int row = m0 + wm + i * 16 + q4;
#pragma unroll
    for (int j = 0; j < 4; j++) {
      const int col = n0 + wn + j * 16 + fr;
      const float bv = bias[col];
#pragma unroll
      for (int q = 0; q < 4; q++) {
        float v = acc[i][j][q] + bv;
        if (OUT_F32) ((float*)C)[(size_t)(row + q) * N + col] = v;
        else         ((f16*)C)[(size_t)(row + q) * N + col] = (f16)v;
      }
    }
  }
}

// ---------------- RoPE: qkv[S][3*HID] -> qh/kh [H][S][DP]; q pre-scaled ----------------
__global__ __launch_bounds__(256) void rope_kernel(const f16* __restrict__ qkvb,
                                                   const float* __restrict__ rpe,
                                                   f16* __restrict__ qh,
                                                   f16* __restrict__ kh) {
  const float SCLT = 0.1118033988749895f * 1.4426950408889634f;  // 1/sqrt(80)*log2(e)
  int t = blockIdx.x * 256 + threadIdx.x;
  if (t >= SEQ * NH * 40) return;
  const int d = t % 40;
  const int h = (t / 40) % NH;
  const int s = t / (40 * NH);
  const float f = rpe[s * 40 + d];
  float sn, cs;
  __sincosf(f, &sn, &cs);
  const size_t base = (size_t)s * (3 * HIDN) + h * HD;
  const float q0 = (float)qkvb[base + d];
  const float q1 = (float)qkvb[base + 40 + d];
  const float k0 = (float)qkvb[base + HIDN + d];
  const float k1 = (float)qkvb[base + HIDN + 40 + d];
  const size_t ob = ((size_t)h * SEQ + s) * DP;
  qh[ob + d]      = (f16)((q0 * cs - q1 * sn) * SCLT);
  qh[ob + 40 + d] = (f16)((q1 * cs + q0 * sn) * SCLT);
  kh[ob + d]      = (f16)(k0 * cs - k1 * sn);
  kh[ob + 40 + d] = (f16)(k1 * cs + k0 * sn);
  if (d < DP - HD) { qh[ob + HD + d] = (f16)0.f; kh[ob + HD + d] = (f16)0.f; }
}

// ---------------- V transpose: qkv v-part -> vt[H][HD][SEQ] ----------------
__global__ __launch_bounds__(256) void vtrans_kernel(const f16* __restrict__ qkvb,
                                                     f16* __restrict__ vt) {
  __shared__ f16 tile[HD][65];
  const int h = blockIdx.y;
  const int s0 = blockIdx.x * 64;
  for (int idx = threadIdx.x; idx < 64 * HD; idx += 256) {
    const int sr = idx / HD, d = idx % HD;
    tile[d][sr] = qkvb[(size_t)(s0 + sr) * (3 * HIDN) + 2 * HIDN + h * HD + d];
  }
  __syncthreads();
  for (int idx = threadIdx.x; idx < HD * 64; idx += 256) {
    const int d = idx >> 6, sc = idx & 63;
    vt[((size_t)h * HD + d) * SEQ + s0 + sc] = tile[d][sc];
  }
}

// ---------------- Flash attention over block-diagonal segments ----------------
__global__ __launch_bounds__(256) void attn_kernel(const f16* __restrict__ qh,
                                                   const f16* __restrict__ kh,
                                                   const f16* __restrict__ vt,
                                                   const int* __restrict__ cu,
                                                   f16* __restrict__ ao) {
  __shared__ __align__(16) f16 Ks[32 * KROWS];
  __shared__ __align__(16) f16 Vs[HD * VROWS];
  __shared__ __align__(16) f16 Ps[4][32 * PROWS];
  const int tid = threadIdx.x, w = tid >> 6, l = tid & 63;
  const int h = blockIdx.y;
  const int row0 = blockIdx.x * 128;
  int seg = 0;
  while (cu[seg + 1] <= row0) seg++;
  const int kvb = cu[seg], kve = cu[seg + 1];

  const int fr = l & 15, fg = (l >> 4) * 8;

  const f16* qb = qh + ((size_t)h * SEQ + row0 + w * 32 + fr) * DP + fg;
  f16x8 aq0[3], aq1[3];
#pragma unroll
  for (int kk = 0; kk < 3; kk++) {
    aq0[kk] = *(const f16x8*)(qb + kk * 32);
    aq1[kk] = *(const f16x8*)(qb + 16 * DP + kk * 32);
  }

  const int kr0 = tid / 12, kg0 = tid % 12;
  const int kr1 = (256 + tid) / 12, kg1 = (256 + tid) % 12;
  const int vr0 = tid >> 2, vg = tid & 3;
  const int vr1 = (256 + tid) >> 2;
  const f16* kp0 = kh + ((size_t)h * SEQ + kvb + kr0) * DP + kg0 * 8;
  const f16* kp1 = kh + ((size_t)h * SEQ + kvb + kr1) * DP + kg1 * 8;
  const f16* vp0 = vt + ((size_t)h * HD + vr0) * SEQ + kvb + vg * 8;
  const f16* vp1 = vt + ((size_t)h * HD + vr1) * SEQ + kvb + vg * 8;
  f16* kl0 = Ks + kr0 * KROWS + kg0 * 8;
  f16* kl1 = Ks + kr1 * KROWS + kg1 * 8;
  f16* vl0 = Vs + vr0 * VROWS + vg * 8;
  f16* vl1 = Vs + vr1 * VROWS + vg * 8;

  uint4 rk0, rk1, rv0, rv1;
  rk0 = *(const uint4*)kp0;
  if (tid < 128) rk1 = *(const uint4*)kp1;
  rv0 = *(const uint4*)vp0;
  if (tid < 64)  rv1 = *(const uint4*)vp1;

  float m = -1e30f;
  float ls0[4] = {0.f, 0.f, 0.f, 0.f}, ls1[4] = {0.f, 0.f, 0.f, 0.f};
  f32x4 o0[5] = {}, o1[5] = {};
  f16* pb = &Ps[w][0];

  for (int kv0 = kvb; kv0 < kve; kv0 += 32) {
    __syncthreads();
    *(uint4*)kl0 = rk0;
    if (tid < 128) *(uint4*)kl1 = rk1;
    *(uint4*)vl0 = rv0;
    if (tid < 64)  *(uint4*)vl1 = rv1;
    __syncthreads();

    const int nxt = kv0 + 32 - kvb;
    if (kv0 + 32 < kve) {
      rk0 = *(const uint4*)(kp0 + (size_t)nxt * DP);
      if (tid < 128) rk1 = *(const uint4*)(kp1 + (size_t)nxt * DP);
      rv0 = *(const uint4*)(vp0 + nxt);
      if (tid < 64)  rv1 = *(const uint4*)(vp1 + nxt);
    }

    f32x4 sA0 = {0.f,0.f,0.f,0.f}, sA1 = {0.f,0.f,0.f,0.f};
    f32x4 sB0 = {0.f,0.f,0.f,0.f}, sB1 = {0.f,0.f,0.f,0.f};
#pragma unroll
    for (int kk = 0; kk < 3; kk++) {
      f16x8 b0 = *(const f16x8*)(Ks + fr * KROWS + kk * 32 + fg);
      f16x8 b1 = *(const f16x8*)(Ks + (16 + fr) * KROWS + kk * 32 + fg);
      sA0 = __builtin_amdgcn_mfma_f32_16x16x32_f16(aq0[kk], b0, sA0, 0, 0, 0);
      sA1 = __builtin_amdgcn_mfma_f32_16x16x32_f16(aq0[kk], b1, sA1, 0, 0, 0);
      sB0 = __builtin_amdgcn_mfma_f32_16x16x32_f16(aq1[kk], b0, sB0, 0, 0, 0);
      sB1 = __builtin_amdgcn_mfma_f32_16x16x32_f16(aq1[kk], b1, sB1, 0, 0, 0);
    }

    float tmax = sA0[0];
#pragma unroll
    for (int j = 0; j < 4; j++) {
      tmax = fmaxf(tmax, fmaxf(sA0[j], sA1[j]));
      tmax = fmaxf(tmax, fmaxf(sB0[j], sB1[j]));
    }
    tmax = fmaxf(tmax, __shfl_xor(tmax, 1));
    tmax = fmaxf(tmax, __shfl_xor(tmax, 2));
    tmax = fmaxf(tmax, __shfl_xor(tmax, 4));
    tmax = fmaxf(tmax, __shfl_xor(tmax, 8));
    tmax = fmaxf(tmax, __shfl_xor(tmax, 16));
    tmax = fmaxf(tmax, __shfl_xor(tmax, 32));

    if (tmax > m + 8.f) {
      const float aa = exp2f(m - tmax);
      m = tmax;
#pragma unroll
      for (int j = 0; j < 4; j++) { ls0[j] *= aa; ls1[j] *= aa; }
#pragma unroll
      for (int dt = 0; dt < 5; dt++)
#pragma unroll
        for (int j = 0; j < 4; j++) { o0[dt][j] *= aa; o1[dt][j] *= aa; }
    }

#pragma unroll
    for (int j = 0; j < 4; j++) {
      const float pA0 = exp2f(sA0[j] - m), pA1 = exp2f(sA1[j] - m);
      const float pB0 = exp2f(sB0[j] - m), pB1 = exp2f(sB1[j] - m);
      ls0[j] += pA0 + pA1;
      ls1[j] += pB0 + pB1;
      const int pr = (l >> 4) * 4 + j;
      pb[pr * PROWS + fr]             = (f16)pA0;
      pb[pr * PROWS + 16 + fr]        = (f16)pA1;
      pb[(16 + pr) * PROWS + fr]      = (f16)pB0;
      pb[(16 + pr) * PROWS + 16 + fr] = (f16)pB1;
    }

    f16x8 paA = *(const f16x8*)(pb + fr * PROWS + fg);
    f16x8 paB = *(const f16x8*)(pb + (16 + fr) * PROWS + fg);
#pragma unroll
    for (int dt = 0; dt < 5; dt++) {
      f16x8 bv = *(const f16x8*)(Vs + (dt * 16 + fr) * VROWS + fg);
      o0[dt] = __builtin_amdgcn_mfma_f32_16x16x32_f16(paA, bv, o0[dt], 0, 0, 0);
      o1[dt] = __builtin_amdgcn_mfma_f32_16x16x32_f16(paB, bv, o1[dt], 0, 0, 0);
    }
  }

#pragma unroll
  for (int j = 0; j < 4; j++) {
    float sa = ls0[j], sb = ls1[j];
    sa += __shfl_xor(sa, 1); sb += __shfl_xor(sb, 1);
    sa += __shfl_xor(sa, 2); sb += __shfl_xor(sb, 2);
    sa += __shfl_xor(sa, 4); sb += __shfl_xor(sb, 4);
    sa += __shfl_xor(sa, 8); sb += __shfl_xor(sb, 8);
    ls0[j] = 1.0f / sa;
    ls1[j] = 1.0f / sb;
  }
  const int orow = row0 + w * 32 + (l >> 4) * 4;
#pragma unroll
  for (int dt = 0; dt < 5; dt++)
#pragma unroll
    for (int j = 0; j < 4; j++) {
      ao[(size_t)(orow + j) * HIDN + h * HD + dt * 16 + fr]      = (f16)(o0[dt][j] * ls0[j]);
      ao[(size_t)(orow + 16 + j) * HIDN + h * HD + dt * 16 + fr] = (f16)(o1[dt][j] * ls1[j]);
    }
}

extern "C" void kernel_launch(void* const* d_in, const int* in_sizes, int n_in,
                              void* d_out, int out_size, void* d_ws, size_t ws_size,
                              hipStream_t stream) {
  const float* x      = (const float*)d_in[0];
  const int*   cu     = (const int*)d_in[1];
  const float* rpe    = (const float*)d_in[2];
  const float* qkv_w  = (const float*)d_in[3];
  const float* qkv_b  = (const float*)d_in[4];
  const float* proj_w = (const float*)d_in[5];
  const float* proj_b = (const float*)d_in[6];

  char* ws = (char*)d_ws;
  f16* xb    = (f16*)(ws);              // [4096][1280]
  f16* wqkv  = (f16*)(ws + 10485760);   // [3840][1280]
  f16* wproj = (f16*)(ws + 20316160);   // [1280][1280]
  f16* qkvb  = (f16*)(ws + 23592960);   // [4096][3840]
  f16* qh    = (f16*)(ws + 55050240);   // [16][4096][96]
  f16* kh    = (f16*)(ws + 67633152);   // [16][4096][96]
  f16* vt    = (f16*)(ws + 80216064);   // [16][80][4096]
  f16* ao    = xb;                      // reuse (xb dead after GEMM1)

  cvt_kernel<<<2560, 256, 0, stream>>>(x, xb, SEQ * HIDN);
  cvt_kernel<<<2400, 256, 0, stream>>>(qkv_w, wqkv, 3 * HIDN * HIDN);
  cvt_kernel<<<800, 256, 0, stream>>>(proj_w, wproj, HIDN * HIDN);

  qkv_gemm8<<<240, 512, 0, stream>>>(xb, wqkv, qkv_b, qkvb);

  rope_kernel<<<(SEQ * NH * 40) / 256, 256, 0, stream>>>(qkvb, rpe, qh, kh);
  vtrans_kernel<<<dim3(SEQ / 64, NH), 256, 0, stream>>>(qkvb, vt);

  attn_kernel<<<dim3(SEQ / 128, NH), 256, 0, stream>>>(qh, kh, vt, cu, ao);

  gemm_bt<1><<<dim3(HIDN / 128, SEQ / 128), 256, 0, stream>>>(
      ao, wproj, proj_b, d_out, SEQ, HIDN, HIDN);
}